// Round 1
// baseline (322.209 us; speedup 1.0000x reference)
//
#include <hip/hip_runtime.h>
#include <cmath>

#define CC 64
#define HH 512
#define WWID 512
#define HWSZ (HH*WWID)
#define DEPTH 4

typedef __attribute__((ext_vector_type(8))) short short8;
typedef __attribute__((ext_vector_type(4))) float floatx4;

__device__ inline unsigned short f2bf(float f){
  unsigned int u = __float_as_uint(f);
  u += 0x7FFF + ((u >> 16) & 1);          // round-to-nearest-even
  return (unsigned short)(u >> 16);
}
__device__ inline float bf2f(unsigned short h){
  return __uint_as_float(((unsigned int)h) << 16);
}

// ---------------- init (+ zero Xf for layer-0 dftw atomics) ----------------
__global__ void k_init(const float* __restrict__ ww,
                       float* __restrict__ ctab, float* __restrict__ stab,
                       unsigned short* __restrict__ trigBh, unsigned short* __restrict__ trigBl,
                       unsigned short* __restrict__ trigTh, unsigned short* __restrict__ trigTl,
                       unsigned short* __restrict__ Whi, unsigned short* __restrict__ Wlo,
                       float4* __restrict__ Xfz){
  if (blockIdx.x < 32) Xfz[blockIdx.x*256 + threadIdx.x] = make_float4(0.f,0.f,0.f,0.f);
  int idx = blockIdx.x*256 + threadIdx.x;
  if (idx < 8192){
    int pos = idx >> 4, k = idx & 15;
    int r = (pos * k) & 511;
    double ang = (2.0 * 3.14159265358979323846 / 512.0) * (double)r;
    float c = (float)cos(ang), s = (float)sin(ang);
    ctab[idx] = c;  stab[idx] = s;
    unsigned short ch = f2bf(c), sh = f2bf(s);
    unsigned short cl = f2bf(c - bf2f(ch)), sl = f2bf(s - bf2f(sh));
    trigBh[pos*32 + 2*k]     = ch;  trigBl[pos*32 + 2*k]     = cl;
    trigBh[pos*32 + 2*k + 1] = sh;  trigBl[pos*32 + 2*k + 1] = sl;
    trigTh[(2*k)*512 + pos]   = ch;  trigTl[(2*k)*512 + pos]   = cl;
    trigTh[(2*k+1)*512 + pos] = sh;  trigTl[(2*k+1)*512 + pos] = sl;
  } else {
    int t = idx - 8192;                   // < 4*64*64, flat [d][o][i]
    float v = ww[t];
    unsigned short h = f2bf(v);
    Whi[t] = h;  Wlo[t] = f2bf(v - bf2f(h));
  }
}

// ---------------- A+B1 fused: DFT along w (MFMA) -> LDS -> h-partial DFT -> atomicAdd Xf ----------------
// Block b: channel i = b>>3, h range [64*(b&7), +64). LIFT=1: read q + on-the-fly lift (layer 0).
#define APITCH 136
#define XPITCH 33
template<int LIFT>
__global__ __launch_bounds__(256) void k_dftw(const float* __restrict__ x,
    const float* __restrict__ qsrc, const float* __restrict__ pw, const float* __restrict__ pb,
    const unsigned short* __restrict__ trigTh, const unsigned short* __restrict__ trigTl,
    const float* __restrict__ ctab, const float* __restrict__ stab,
    float* __restrict__ Xfa, float4* __restrict__ Yz){
  if (blockIdx.x < 32) Yz[blockIdx.x*256 + threadIdx.x] = make_float4(0.f,0.f,0.f,0.f);

  __shared__ unsigned short Ahs[64*APITCH], Als[64*APITCH];
  __shared__ unsigned short Bhs[32*APITCH], Bls[32*APITCH];
  __shared__ float X1s[64*XPITCH];            // [hh][j]: j=2n -> Re, 2n+1 -> Im
  int row0 = blockIdx.x * 64;                 // rows = i*512 + h
  int i  = row0 >> 9;
  int h0 = row0 & 511;
  int t = threadIdx.x;
  int g = t >> 6, lm = t & 15, lq = (t >> 4) & 3;
  float pa = 0.f, pbv = 0.f;
  if (LIFT){ pa = pw[i]; pbv = pb[i]; }       // block-uniform scalars

  floatx4 acc[2] = {{0.f,0.f,0.f,0.f},{0.f,0.f,0.f,0.f}};

  for (int kc = 0; kc < 4; ++kc){             // K chunks of 128
    {                                         // stage A: 64 rows x 128 k, fp32 -> split bf16
      int r = t >> 2, qq = t & 3;
      const float4* src4 = LIFT
        ? (const float4*)(qsrc + (size_t)(h0 + r)*512 + kc*128 + qq*32)
        : (const float4*)(x    + (size_t)(row0 + r)*512 + kc*128 + qq*32);
      unsigned int* dh = (unsigned int*)&Ahs[r*APITCH + qq*32];
      unsigned int* dl = (unsigned int*)&Als[r*APITCH + qq*32];
      #pragma unroll
      for (int u = 0; u < 8; ++u){
        float4 v = src4[u];
        if (LIFT){
          v.x = fmaf(pa, v.x, pbv); v.y = fmaf(pa, v.y, pbv);
          v.z = fmaf(pa, v.z, pbv); v.w = fmaf(pa, v.w, pbv);
        }
        unsigned short h0_ = f2bf(v.x), h1 = f2bf(v.y), h2 = f2bf(v.z), h3 = f2bf(v.w);
        dh[u*2]   = (unsigned)h0_ | ((unsigned)h1 << 16);
        dh[u*2+1] = (unsigned)h2 | ((unsigned)h3 << 16);
        unsigned short g0 = f2bf(v.x - bf2f(h0_)), g1 = f2bf(v.y - bf2f(h1));
        unsigned short g2 = f2bf(v.z - bf2f(h2)), g3 = f2bf(v.w - bf2f(h3));
        dl[u*2]   = (unsigned)g0 | ((unsigned)g1 << 16);
        dl[u*2+1] = (unsigned)g2 | ((unsigned)g3 << 16);
      }
    }
    {                                         // stage B: 32 rows x 128 k (bf16 copy)
      int j = t >> 3, qq = t & 7;
      const unsigned int* sh = (const unsigned int*)trigTh + j*256 + kc*64 + qq*8;
      const unsigned int* sl = (const unsigned int*)trigTl + j*256 + kc*64 + qq*8;
      unsigned int* dh = (unsigned int*)&Bhs[j*APITCH + qq*16];
      unsigned int* dl = (unsigned int*)&Bls[j*APITCH + qq*16];
      #pragma unroll
      for (int u = 0; u < 8; ++u){ dh[u] = sh[u]; dl[u] = sl[u]; }
    }
    __syncthreads();
    #pragma unroll
    for (int ks = 0; ks < 4; ++ks){
      short8 ah = *(const short8*)&Ahs[(g*16 + lm)*APITCH + ks*32 + lq*8];
      short8 al = *(const short8*)&Als[(g*16 + lm)*APITCH + ks*32 + lq*8];
      #pragma unroll
      for (int nt = 0; nt < 2; ++nt){
        short8 bh = *(const short8*)&Bhs[(nt*16 + lm)*APITCH + ks*32 + lq*8];
        short8 bl = *(const short8*)&Bls[(nt*16 + lm)*APITCH + ks*32 + lq*8];
        acc[nt] = __builtin_amdgcn_mfma_f32_16x16x32_bf16(ah, bh, acc[nt], 0, 0, 0);
        acc[nt] = __builtin_amdgcn_mfma_f32_16x16x32_bf16(ah, bl, acc[nt], 0, 0, 0);
        acc[nt] = __builtin_amdgcn_mfma_f32_16x16x32_bf16(al, bh, acc[nt], 0, 0, 0);
      }
    }
    __syncthreads();
  }
  // D -> LDS (sign-folded): row hh = g*16+lq*4+rg, col j = nt*16+lm; odd j negated
  #pragma unroll
  for (int nt = 0; nt < 2; ++nt){
    int j = nt*16 + lm;
    float sgn = (j & 1) ? -1.f : 1.f;
    #pragma unroll
    for (int rg = 0; rg < 4; ++rg){
      int m = g*16 + lq*4 + rg;
      X1s[m*XPITCH + j] = sgn * acc[nt][rg];
    }
  }
  __syncthreads();

  // h-partial DFT: thread (mo,n) sums its 64 h's, atomicAdd into Xf[i][mn]
  int mo = t >> 4, n = t & 15;
  float ar = 0.f, ai = 0.f;
  #pragma unroll 8
  for (int hh = 0; hh < 64; ++hh){
    int h = h0 + hh;
    float Re = X1s[hh*XPITCH + 2*n];
    float Im = X1s[hh*XPITCH + 2*n + 1];
    float c = ctab[h*16 + mo], s = stab[h*16 + mo];
    ar += Re*c + Im*s;
    ai += Im*c - Re*s;
  }
  atomicAdd(&Xfa[(i*256 + t)*2],     ar);
  atomicAdd(&Xfa[(i*256 + t)*2 + 1], ai);
}

// ---------------- B2: mode contraction, i-chunked, mn-split; atomicAdd into Y ----------------
__global__ void k_contract(const float2* __restrict__ Xf,
                           const float* __restrict__ wr, const float* __restrict__ wi,
                           float* __restrict__ Ya){
  int o = blockIdx.x, ic = blockIdx.y;
  int mn = blockIdx.z*64 + threadIdx.x;
  float ar = 0.f, ai = 0.f;
  int i0 = ic * 16;
  #pragma unroll
  for (int ii = 0; ii < 16; ++ii){
    int i = i0 + ii;
    float2 xf = Xf[i*256 + mn];
    float wrv = wr[(i*64 + o)*256 + mn];
    float wiv = wi[(i*64 + o)*256 + mn];
    ar += xf.x*wrv - xf.y*wiv;
    ai += xf.x*wiv + xf.y*wrv;
  }
  const float sc = 1.f/262144.f;
  atomicAdd(&Ya[(o*256 + mn)*2],     ar*sc);
  atomicAdd(&Ya[(o*256 + mn)*2 + 1], ai*sc);
}

// ---------------- B3: iDFT along h -> T split bf16; zero-Xf tail (next layer's accumulator) ----------------
__global__ void k_idfth(const float2* __restrict__ Y, const float* __restrict__ ct,
                        const float* __restrict__ st,
                        unsigned int* __restrict__ Thi, unsigned int* __restrict__ Tlo,
                        float4* __restrict__ Xfz){
  if (blockIdx.x < 32) Xfz[blockIdx.x*256 + threadIdx.x] = make_float4(0.f,0.f,0.f,0.f);
  int idx = blockIdx.x*256 + threadIdx.x;     // (h*64+o)*16+n
  int n = idx & 15, o = (idx >> 4) & 63, h = idx >> 10;
  float ar = 0.f, ai = 0.f;
  #pragma unroll
  for (int m = 0; m < 16; ++m){
    float2 y = Y[(o<<8) + (m<<4) + n];
    float c = ct[h*16 + m], s = st[h*16 + m];
    ar += y.x*c - y.y*s;
    ai += y.x*s + y.y*c;
  }
  float tr = ar, ts = -ai;
  unsigned short rh = f2bf(tr), sh = f2bf(ts);
  Thi[idx] = (unsigned int)rh | ((unsigned int)sh << 16);   // [2n]=Tr low, [2n+1]=-Ti high
  unsigned short rl = f2bf(tr - bf2f(rh)), slr = f2bf(ts - bf2f(sh));
  Tlo[idx] = (unsigned int)rl | ((unsigned int)slr << 16);
}

// ---------------- C: combine GEMM (K=96), split-bf16 3-pass, 64o x 128w tiles ----------------
// A (o x 96: W | T[h]) staged ONCE per block now serves 128 w columns (was 64) —
// halves A-side staging traffic and per-block fixed cost per output element.
// LDS: (64+64+128+128)*104*2 = 79872 B -> exactly 2 blocks/CU (160 KiB).
// LIFT=1: x-stage computes lift(q) on the fly (layer 0). FINAL=1: skip x store,
// reduce sum_o fw[o]*gelu -> out (layer 3; fuses k_final). fred aliases Ah (dead after MFMA).
#define PITCH 104
template<int LIFT, int FINAL>
__global__ __launch_bounds__(256) void k_combine(
    const float* __restrict__ x, const float* __restrict__ qsrc,
    const float* __restrict__ pw, const float* __restrict__ pb,
    const unsigned short* __restrict__ Whid, const unsigned short* __restrict__ Wlod,
    const unsigned int* __restrict__ Thi,  const unsigned int* __restrict__ Tlo,
    const unsigned short* __restrict__ trigBh, const unsigned short* __restrict__ trigBl,
    const float* __restrict__ wb, float* __restrict__ xo,
    const float* __restrict__ fw, const float* __restrict__ fb,
    float* __restrict__ outp)
{
  __shared__ unsigned short Ah[64*PITCH],  Al[64*PITCH];    // rows o, k 0..95
  __shared__ unsigned short Bh[128*PITCH], Bl[128*PITCH];   // rows w(pixel), k 0..95
  int h  = blockIdx.y;
  int w0 = blockIdx.x * 128;
  int t  = threadIdx.x;

  {   // B x-part: 128 pixels x 64 channels; thread = (pixel wl, channel-half ig)
    int wl = t & 127, ig = t >> 7;
    if (LIFT){
      float qv = qsrc[(size_t)h*512 + w0 + wl];
      #pragma unroll
      for (int ii = 0; ii < 32; ii += 2){
        int i0 = ig*32 + ii;
        float v0 = fmaf(pw[i0],   qv, pb[i0]);
        float v1 = fmaf(pw[i0+1], qv, pb[i0+1]);
        unsigned short h0 = f2bf(v0), h1 = f2bf(v1);
        unsigned short g0 = f2bf(v0 - bf2f(h0)), g1 = f2bf(v1 - bf2f(h1));
        *(unsigned int*)&Bh[wl*PITCH + i0] = (unsigned int)h0 | ((unsigned int)h1 << 16);
        *(unsigned int*)&Bl[wl*PITCH + i0] = (unsigned int)g0 | ((unsigned int)g1 << 16);
      }
    } else {
      const float* xb = x + (size_t)h*512 + w0 + wl;
      #pragma unroll
      for (int ii = 0; ii < 32; ii += 2){
        int i0 = ig*32 + ii;
        float v0 = xb[(size_t)i0*HWSZ];
        float v1 = xb[(size_t)(i0+1)*HWSZ];
        unsigned short h0 = f2bf(v0), h1 = f2bf(v1);
        unsigned short g0 = f2bf(v0 - bf2f(h0)), g1 = f2bf(v1 - bf2f(h1));
        *(unsigned int*)&Bh[wl*PITCH + i0] = (unsigned int)h0 | ((unsigned int)h1 << 16);
        *(unsigned int*)&Bl[wl*PITCH + i0] = (unsigned int)g0 | ((unsigned int)g1 << 16);
      }
    }
  }
  {   // B trig-part: rows w (128), k=64..95
    int row = t >> 1, qq = t & 1;
    const unsigned int* sh = (const unsigned int*)trigBh + (size_t)(w0+row)*16 + qq*8;
    const unsigned int* sl = (const unsigned int*)trigBl + (size_t)(w0+row)*16 + qq*8;
    unsigned int* dh = (unsigned int*)&Bh[row*PITCH + 64] + qq*8;
    unsigned int* dl = (unsigned int*)&Bl[row*PITCH + 64] + qq*8;
    #pragma unroll
    for (int u = 0; u < 8; ++u){ dh[u] = sh[u]; dl[u] = sl[u]; }
  }
  {   // A W-part: rows o, k=0..63
    int o = t >> 2, q8 = t & 3;
    const unsigned int* sh = (const unsigned int*)Whid + o*32 + q8*8;
    const unsigned int* sl = (const unsigned int*)Wlod + o*32 + q8*8;
    unsigned int* dh = (unsigned int*)&Ah[o*PITCH] + q8*8;
    unsigned int* dl = (unsigned int*)&Al[o*PITCH] + q8*8;
    #pragma unroll
    for (int u = 0; u < 8; ++u){ dh[u] = sh[u]; dl[u] = sl[u]; }
  }
  {   // A T-part: rows o, k=64..95
    int o = t >> 2, q4 = t & 3;
    const unsigned int* sh = Thi + (size_t)h*1024 + o*16 + q4*4;
    const unsigned int* sl = Tlo + (size_t)h*1024 + o*16 + q4*4;
    unsigned int* dh = (unsigned int*)&Ah[o*PITCH + 64] + q4*4;
    unsigned int* dl = (unsigned int*)&Al[o*PITCH + 64] + q4*4;
    #pragma unroll
    for (int u = 0; u < 4; ++u){ dh[u] = sh[u]; dl[u] = sl[u]; }
  }
  __syncthreads();

  int g  = t >> 6;          // wave -> m-tile (o-rows g*16..+15)
  int lm = t & 15;
  int lq = (t >> 4) & 3;

  floatx4 acc[8] = {{0.f,0.f,0.f,0.f},{0.f,0.f,0.f,0.f},{0.f,0.f,0.f,0.f},{0.f,0.f,0.f,0.f},
                    {0.f,0.f,0.f,0.f},{0.f,0.f,0.f,0.f},{0.f,0.f,0.f,0.f},{0.f,0.f,0.f,0.f}};

  #pragma unroll
  for (int ks = 0; ks < 3; ++ks){
    short8 af = *(const short8*)&Ah[(g*16 + lm)*PITCH + ks*32 + lq*8];
    short8 al = *(const short8*)&Al[(g*16 + lm)*PITCH + ks*32 + lq*8];
    #pragma unroll
    for (int nt = 0; nt < 8; ++nt){
      short8 bf = *(const short8*)&Bh[(nt*16 + lm)*PITCH + ks*32 + lq*8];
      short8 bl = *(const short8*)&Bl[(nt*16 + lm)*PITCH + ks*32 + lq*8];
      acc[nt] = __builtin_amdgcn_mfma_f32_16x16x32_bf16(af, bf, acc[nt], 0, 0, 0);
      acc[nt] = __builtin_amdgcn_mfma_f32_16x16x32_bf16(af, bl, acc[nt], 0, 0, 0);
      acc[nt] = __builtin_amdgcn_mfma_f32_16x16x32_bf16(al, bf, acc[nt], 0, 0, 0);
    }
  }

  if (!FINAL){
    // epilogue: bias + tanh-gelu + fp32 in-place store
    #pragma unroll
    for (int nt = 0; nt < 8; ++nt){
      int w = w0 + nt*16 + lm;
      #pragma unroll
      for (int rg = 0; rg < 4; ++rg){
        int o = g*16 + lq*4 + rg;
        float u = acc[nt][rg] + wb[o];
        float z = 0.7978845608028654f * fmaf(0.044715f, u*u*u, u);
        float e = __expf(2.f*z);
        float gl = u - __fdividef(u, e + 1.f);
        xo[(size_t)o*HWSZ + (size_t)h*512 + w] = gl;
      }
    }
  } else {
    // epilogue: bias + gelu + final projection reduced in-block (fuses k_final).
    // fred aliases Ah (A operands fully consumed by MFMA loop above).
    float* fred = (float*)Ah;                 // needs 128*17*4 = 8704 B <= 13312 B
    __syncthreads();                          // all waves done READING Ah before overwrite
    #pragma unroll
    for (int nt = 0; nt < 8; ++nt){
      float partial = 0.f;
      #pragma unroll
      for (int rg = 0; rg < 4; ++rg){
        int o = g*16 + lq*4 + rg;
        float u = acc[nt][rg] + wb[o];
        float z = 0.7978845608028654f * fmaf(0.044715f, u*u*u, u);
        float e = __expf(2.f*z);
        float gl = u - __fdividef(u, e + 1.f);
        partial = fmaf(fw[o], gl, partial);
      }
      fred[(nt*16 + lm)*17 + (t >> 4)] = partial;
    }
    __syncthreads();
    if (t < 128){
      float s = fb[0];
      #pragma unroll
      for (int k2 = 0; k2 < 16; ++k2) s += fred[t*17 + k2];
      outp[(size_t)h*512 + w0 + t] = s;
    }
  }
}

extern "C" void kernel_launch(void* const* d_in, const int* in_sizes, int n_in,
                              void* d_out, int out_size, void* d_ws, size_t ws_size,
                              hipStream_t stream) {
  const float* q       = (const float*)d_in[0];
  const float* proj_w  = (const float*)d_in[1];
  const float* proj_b  = (const float*)d_in[2];
  const float* spec_wr = (const float*)d_in[3];
  const float* spec_wi = (const float*)d_in[4];
  const float* w_w     = (const float*)d_in[5];
  const float* w_b     = (const float*)d_in[6];
  const float* final_w = (const float*)d_in[7];
  const float* final_b = (const float*)d_in[8];
  float* out = (float*)d_out;

  // Workspace (bytes, end-exclusive) — unchanged:
  //   ctab   [       0,   32768)
  //   stab   [   32768,   65536)
  //   trigBh [   65536,   98304)   trigBl [   98304,  131072)
  //   Thi    [  131072,  2228224)  Tlo [ 2228224,  4325376)
  //   Xf     [ 4325376,  4456448)  128 KiB (dftw atomics; zeroed by init/idfth tails)
  //   Y      [ 4456448,  4587520)  128 KiB (contract atomics; zeroed by dftw tail)
  //   x      [ 4587520, 71696384)  64 MiB fp32 (layers 0-2 activations)
  //   Whi    [71696384, 71729152)  Wlo [71729152, 71761920)
  //   trigTh [71761920, 71794688)  trigTl [71794688, 71827456)   total ~68.5 MiB
  char* ws = (char*)d_ws;
  float*  ctab = (float*) (ws + 0);
  float*  stab = (float*) (ws + 32768);
  unsigned short* trigBh = (unsigned short*)(ws + 65536);
  unsigned short* trigBl = (unsigned short*)(ws + 98304);
  unsigned int* Thi = (unsigned int*)(ws + 131072);
  unsigned int* Tlo = (unsigned int*)(ws + 2228224);
  float*  Xf   = (float*) (ws + 4325376);
  float*  Y    = (float*) (ws + 4456448);
  float*  x    = (float*) (ws + 4587520);
  unsigned short* Whi = (unsigned short*)(ws + 71696384);
  unsigned short* Wlo = (unsigned short*)(ws + 71729152);
  unsigned short* trigTh = (unsigned short*)(ws + 71761920);
  unsigned short* trigTl = (unsigned short*)(ws + 71794688);

  k_init<<<96, 256, 0, stream>>>(w_w, ctab, stab, trigBh, trigBl, trigTh, trigTl,
                                 Whi, Wlo, (float4*)Xf);

  for (int d = 0; d < DEPTH; ++d){
    if (d == 0)
      k_dftw<1><<<512, 256, 0, stream>>>(x, q, proj_w, proj_b, trigTh, trigTl,
                                         ctab, stab, Xf, (float4*)Y);
    else
      k_dftw<0><<<512, 256, 0, stream>>>(x, q, proj_w, proj_b, trigTh, trigTl,
                                         ctab, stab, Xf, (float4*)Y);
    k_contract<<<dim3(64,4,4), 64, 0, stream>>>((const float2*)Xf,
                                                spec_wr + (size_t)d*1048576,
                                                spec_wi + (size_t)d*1048576, Y);
    k_idfth<<<2048, 256, 0, stream>>>((const float2*)Y, ctab, stab, Thi, Tlo,
                                      (float4*)Xf);
    if (d == 0)
      k_combine<1,0><<<dim3(4,512), 256, 0, stream>>>(x, q, proj_w, proj_b,
          Whi + d*4096, Wlo + d*4096, Thi, Tlo, trigBh, trigBl,
          w_b + d*64, x, final_w, final_b, out);
    else if (d < DEPTH-1)
      k_combine<0,0><<<dim3(4,512), 256, 0, stream>>>(x, q, proj_w, proj_b,
          Whi + d*4096, Wlo + d*4096, Thi, Tlo, trigBh, trigBl,
          w_b + d*64, x, final_w, final_b, out);
    else
      k_combine<0,1><<<dim3(4,512), 256, 0, stream>>>(x, q, proj_w, proj_b,
          Whi + d*4096, Wlo + d*4096, Thi, Tlo, trigBh, trigBl,
          w_b + d*64, x, final_w, final_b, out);
  }
}